// Round 1
// baseline (837.587 us; speedup 1.0000x reference)
//
#include <hip/hip_runtime.h>
#include <stddef.h>

// Problem constants (AnatomicalTextEnhancer): B=16, R=29, D=512, N=20000, k=5
#define B_ 16
#define R_ 29
#define D_ 512
#define N_ 20000
#define K_ 5
#define TILE_N 256
#define NBLK ((N_ + TILE_N - 1) / TILE_N)   // 79
#define CH 32                                // d-chunk (floats)
#define NCH (D_ / CH)                        // 16
#define NEG_MASK (-1.0e9f)
#define SENT (-3.0e38f)

// ---------------------------------------------------------------------------
// Kernel 1: L2-normalize queries, write transposed layout qn[r][b][d]
// ---------------------------------------------------------------------------
__global__ __launch_bounds__(64) void knorm_kernel(const float* __restrict__ q,
                                                   float* __restrict__ qn) {
    int pair = blockIdx.x;          // 0 .. B*R-1
    int b = pair / R_;
    int r = pair % R_;
    int lane = threadIdx.x;
    const float4* src = (const float4*)(q + ((size_t)(b * R_ + r)) * D_);
    float4 x0 = src[lane * 2];
    float4 x1 = src[lane * 2 + 1];
    float ss = x0.x * x0.x + x0.y * x0.y + x0.z * x0.z + x0.w * x0.w +
               x1.x * x1.x + x1.y * x1.y + x1.z * x1.z + x1.w * x1.w;
#pragma unroll
    for (int off = 32; off; off >>= 1) ss += __shfl_xor(ss, off);
    float inv = 1.0f / fmaxf(sqrtf(ss), 1e-12f);
    float4 y0, y1;
    y0.x = x0.x * inv; y0.y = x0.y * inv; y0.z = x0.z * inv; y0.w = x0.w * inv;
    y1.x = x1.x * inv; y1.y = x1.y * inv; y1.z = x1.z * inv; y1.w = x1.w * inv;
    float4* dst = (float4*)(qn + ((size_t)(r * B_ + b)) * D_);
    dst[lane * 2] = y0;
    dst[lane * 2 + 1] = y1;
}

// ---------------------------------------------------------------------------
// Kernel 2: per (r, n-tile) block: sims for all 16 b, mask, per-block top-5/b
// ---------------------------------------------------------------------------
__global__ __launch_bounds__(256) void ksim_kernel(const float* __restrict__ kb,
                                                   const float* __restrict__ qn,
                                                   const int* __restrict__ qid,
                                                   const int* __restrict__ kbid,
                                                   float* __restrict__ pvals,
                                                   int* __restrict__ pidx) {
    // 32 KB LDS: kb tile [256 rows][8 float4] (XOR-swizzled), reused for sims
    __shared__ float4 smem4[TILE_N * 8];
    float* smemf = (float*)smem4;

    const int r = blockIdx.y;
    const int n0 = blockIdx.x * TILE_N;
    const int tid = threadIdx.x;
    const int row = tid;                 // this thread's kb row within tile
    const int n = n0 + row;
    const size_t kbbase = (size_t)r * N_ * D_;
    const float* qr = qn + (size_t)r * B_ * D_;   // wave-uniform panel

    float acc[B_];
#pragma unroll
    for (int b = 0; b < B_; ++b) acc[b] = 0.0f;
    float nrm = 0.0f;

    const int lrow = tid >> 3;           // 0..31 (staging row group)
    const int lk = tid & 7;              // float4 slot within 32-float chunk
    const int lswz = lrow & 7;           // (lrow + i*32) & 7 == lrow & 7

    for (int c = 0; c < NCH; ++c) {
        __syncthreads();
        // stage [256][32] fp32 chunk, coalesced 128B groups, swizzled LDS dest
#pragma unroll
        for (int i = 0; i < 8; ++i) {
            int srow = lrow + i * 32;
            int gn = n0 + srow;
            float4 v = make_float4(0.f, 0.f, 0.f, 0.f);
            if (gn < N_)
                v = *(const float4*)(kb + kbbase + (size_t)gn * D_ + c * CH + lk * 4);
            smem4[srow * 8 + (lk ^ lswz)] = v;
        }
        __syncthreads();
        // compute: lane-per-row, q from uniform (scalar) loads
#pragma unroll
        for (int g = 0; g < 8; ++g) {
            float4 kv = smem4[row * 8 + (g ^ (row & 7))];
            nrm += kv.x * kv.x + kv.y * kv.y + kv.z * kv.z + kv.w * kv.w;
#pragma unroll
            for (int b = 0; b < B_; ++b) {
                const float4 qv = *(const float4*)(qr + b * D_ + c * CH + g * 4);
                acc[b] += kv.x * qv.x + kv.y * qv.y + kv.z * qv.z + kv.w * qv.w;
            }
        }
    }

    // finalize sims: normalize by ||kb||, mask same-image, tail sentinel
    float rinv = 1.0f / fmaxf(sqrtf(nrm), 1e-12f);
    int myid = (n < N_) ? kbid[(size_t)r * N_ + n] : -1;
    __syncthreads();   // done with kb tile; reuse LDS for sims[16][256]
#pragma unroll
    for (int b = 0; b < B_; ++b) {
        float s = acc[b] * rinv;
        if (myid == qid[b]) s = NEG_MASK;
        if (n >= N_) s = SENT;
        smemf[b * TILE_N + row] = s;
    }
    __syncthreads();

    // per-block top-5 per b: wave w handles b = 4w .. 4w+3
    const int wave = tid >> 6;
    const int lane = tid & 63;
    for (int bi = 0; bi < 4; ++bi) {
        int b = wave * 4 + bi;
        float v[4];
        int ix[4];
#pragma unroll
        for (int j = 0; j < 4; ++j) {
            v[j] = smemf[b * TILE_N + lane + 64 * j];
            ix[j] = n0 + lane + 64 * j;
        }
#pragma unroll
        for (int k = 0; k < K_; ++k) {
            float bv = v[0];
            int bx = ix[0];
#pragma unroll
            for (int j = 1; j < 4; ++j)
                if (v[j] > bv || (v[j] == bv && ix[j] < bx)) { bv = v[j]; bx = ix[j]; }
#pragma unroll
            for (int off = 32; off; off >>= 1) {
                float ov = __shfl_xor(bv, off);
                int ox = __shfl_xor(bx, off);
                if (ov > bv || (ov == bv && ox < bx)) { bv = ov; bx = ox; }
            }
            if (lane == 0) {
                size_t o = (((size_t)r * NBLK + blockIdx.x) * B_ + b) * K_ + k;
                pvals[o] = bv;
                pidx[o] = bx;
            }
#pragma unroll
            for (int j = 0; j < 4; ++j)
                if (ix[j] == bx) v[j] = SENT;   // remove winner, next extraction
        }
    }
}

// ---------------------------------------------------------------------------
// Kernel 3: reduce NBLK*5 candidates per (b,r) to final top-5; write outputs
// d_out layout (all float32): scores[B][R] | vals[B][R][5] | idx[B][R][5]
// ---------------------------------------------------------------------------
__global__ __launch_bounds__(64) void ktop_kernel(const float* __restrict__ pvals,
                                                  const int* __restrict__ pidx,
                                                  float* __restrict__ out) {
    int pair = blockIdx.x;      // 0 .. B*R-1
    int b = pair / R_;
    int r = pair % R_;
    int lane = threadIdx.x;
    const int P = NBLK * K_;    // 395
    float v[7];
    int ix[7];
#pragma unroll
    for (int j = 0; j < 7; ++j) {
        int c = lane + 64 * j;
        if (c < P) {
            size_t o = (((size_t)r * NBLK + (c / K_)) * B_ + b) * K_ + (c % K_);
            v[j] = pvals[o];
            ix[j] = pidx[o];
        } else {
            v[j] = SENT;
            ix[j] = 0x7fffffff;
        }
    }
#pragma unroll
    for (int k = 0; k < K_; ++k) {
        float bv = v[0];
        int bx = ix[0];
#pragma unroll
        for (int j = 1; j < 7; ++j)
            if (v[j] > bv || (v[j] == bv && ix[j] < bx)) { bv = v[j]; bx = ix[j]; }
#pragma unroll
        for (int off = 32; off; off >>= 1) {
            float ov = __shfl_xor(bv, off);
            int ox = __shfl_xor(bx, off);
            if (ov > bv || (ov == bv && ox < bx)) { bv = ov; bx = ox; }
        }
        if (lane == 0) {
            int p = b * R_ + r;
            if (k == 0) out[p] = bv;                       // similarity_scores
            out[B_ * R_ + (size_t)p * K_ + k] = bv;        // top_vals
            out[B_ * R_ + (size_t)B_ * R_ * K_ + (size_t)p * K_ + k] = (float)bx; // top_idx
        }
#pragma unroll
        for (int j = 0; j < 7; ++j)
            if (ix[j] == bx) v[j] = SENT;
    }
}

// ---------------------------------------------------------------------------
extern "C" void kernel_launch(void* const* d_in, const int* in_sizes, int n_in,
                              void* d_out, int out_size, void* d_ws, size_t ws_size,
                              hipStream_t stream) {
    const float* q    = (const float*)d_in[0];   // [B,R,D] fp32
    const float* kb   = (const float*)d_in[1];   // [R,N,D] fp32
    const int*   qid  = (const int*)d_in[2];     // [B]
    const int*   kbid = (const int*)d_in[3];     // [R,N]
    float* out = (float*)d_out;

    float* qn    = (float*)d_ws;                             // R*B*D floats
    float* pvals = qn + (size_t)R_ * B_ * D_;                // R*NBLK*B*K floats
    int*   pidx  = (int*)(pvals + (size_t)R_ * NBLK * B_ * K_);

    knorm_kernel<<<B_ * R_, 64, 0, stream>>>(q, qn);
    dim3 g2(NBLK, R_);
    ksim_kernel<<<g2, 256, 0, stream>>>(kb, qn, qid, kbid, pvals, pidx);
    ktop_kernel<<<B_ * R_, 64, 0, stream>>>(pvals, pidx, out);
}